// Round 5
// baseline (396.421 us; speedup 1.0000x reference)
//
#include <hip/hip_runtime.h>

// CausalSelfAttention: x[4,2048,1024] fp32 -> out fp32
// Pipeline (all bf16 MFMA, fp32 accum):
//  1) cvt x -> bf16            2) transpose+cvt W_attn & W_proj -> bf16 [N][K]
//  3) gemm8p (128x256 tile, BK=32, 2-phase/tile counted-vmcnt schedule,
//     768 blocks = 3/CU uniform) -> Q (pre-scaled by 0.125*log2e), K,
//     V TRANSPOSED [b,h,d,s] (scatter)
//  4) flash attention: 128 q-rows/block (4 waves x 32), XCD head-affinity
//     swizzle, fixed-max softmax (P = 2^s), K/Vt direct-to-LDS w/ XOR swizzle.
//  5) gemm_proj (128x64 tile, 1024 blocks, 3/CU) + bias -> out fp32
//
// R5 post-mortem of R4 (259us; QKV 79us, conflicts 0, LDS=64KB applied but
// Occupancy STILL 14.5%, dur flat):
//   grid=384 is not a multiple of 256 CUs: 2-blocks/CU capacity puts 2 blocks
//   on 128 CUs, 1 on the rest -> half the chip does DOUBLE work; makespan
//   = 2 block-units, same as 1/CU. The LDS fix bought capacity the grid
//   shape can't use.
//   FIX: retile 256x256 -> 128x256 (64x12 = 768 blocks = 3x256 exactly).
//   256 thr / 4 waves (1Mx4N), per-wave 128x64 out (acc[8][4], unchanged
//   per-wave profile). LDS 48KB -> 3 blocks/CU uniform (144<=160KB), work
//   1.5 units/CU (-25% floor) + 3-way TLP covering barrier/vmcnt stalls.
// Schedule per K-tile (guide T3+T4+T5, counted vmcnt, never 0 in loop):
//   P0 {RD_A x8, RD_B 0-1, issue A1/B0/B1/B2(t+1), BAR, setprio1, 16 MFMA,
//       setprio0, BAR}
//   P1 {RD_B 2-3, issue B3(t+1)/A0(t+2), vmcnt(1), BAR, setprio1, 16 MFMA,
//       setprio0, BAR}
//   steady state: 7 outstanding -> drain to 1: t+1 fully landed, A0(t+2)
//   in flight. Overwrite safety: A reads complete in P0 (consumed by MFMA,
//   lgkmcnt) before P0's trailing barrier; A0(t+2) (same-parity buffer,
//   rows 0-63) issued in P1. B(t+1) writes other-parity buffer whose reads
//   finished in tile t-1. Tail issues clamped (identical-data reload).
// Rotation swizzle (conflict-free, verified R3): writer puts logical chunk
//   ((t&3)-((t>>3)&3))&3 in slot t&3; reader slot (quad+(l15>>1))&3.
//   Bank-quad covers all 8 quads 2x over 16 lanes -> 2-way = free (m136).
// MFMA 16x16x32 bf16 layouts (HW-verified per guide):
//   A: a[j] = A[m=lane&15][k=quad*8+j]  (quad=lane>>4)
//   B: b[j] = B[k=quad*8+j][n=lane&15]  (from Bt[n][k] read at row n)
//   C/D: c[i] = D[row=quad*4+i][col=lane&15]

#define BATCH 4
#define SEQ   2048
#define EMB   1024
#define NH    16
#define HD    64

typedef __bf16 bf16;
typedef __bf16 bf16x8 __attribute__((ext_vector_type(8)));
typedef float  f32x4  __attribute__((ext_vector_type(4)));

// direct global->LDS 16B copy: LDS dest is wave-uniform base + lane*16
__device__ __forceinline__ void ld_lds16(const void* g, void* l) {
  __builtin_amdgcn_global_load_lds(
      (const __attribute__((address_space(1))) void*)g,
      (__attribute__((address_space(3))) void*)l, 16, 0, 0);
}

// ---------------- convert fp32 -> bf16 ----------------
__global__ void cvt_f32_bf16(const float* __restrict__ in, bf16* __restrict__ out, int n) {
  int i = (blockIdx.x * blockDim.x + threadIdx.x) * 4;
  if (i + 3 < n) {
    float4 v = *(const float4*)(in + i);
    bf16 o0 = (bf16)v.x, o1 = (bf16)v.y, o2 = (bf16)v.z, o3 = (bf16)v.w;
    out[i] = o0; out[i+1] = o1; out[i+2] = o2; out[i+3] = o3;
  }
}

// ---------------- transpose + convert both weights (one launch) ----------------
__global__ void transpose_cvt2(const float* __restrict__ Wa, const float* __restrict__ Wp,
                               bf16* __restrict__ WaT, bf16* __restrict__ WpT) {
  __shared__ float tile[32][33];
  int bx = blockIdx.x;
  const float* W; bf16* WT; int N;
  if (bx < 96) { W = Wa; WT = WaT; N = 3072; }
  else         { W = Wp; WT = WpT; N = 1024; bx -= 96; }
  int n0 = bx * 32, k0 = blockIdx.y * 32;
  int tx = threadIdx.x & 31, ty = threadIdx.x >> 5;
#pragma unroll
  for (int r = 0; r < 4; r++) {
    int k = k0 + ty + r * 8;
    tile[ty + r * 8][tx] = W[(long)k * N + n0 + tx];
  }
  __syncthreads();
#pragma unroll
  for (int r = 0; r < 4; r++) {
    int n = n0 + ty + r * 8;
    WT[(long)n * EMB + k0 + tx] = (bf16)tile[tx][ty + r * 8];
  }
}

#define QSCALE 0.18033688f   // (1/8) * log2(e)

// ---------------- 128x256 phase-pipelined QKV GEMM ----------------
// A[8192][1024] bf16 x Bt[3072][1024] bf16 + bias -> Q/K/V.
// Grid 768 (=3x256, uniform 3 blocks/CU) x 256 thr (4 waves, 1Mx4N).
__global__ __launch_bounds__(256, 3) void gemm8p(
    const bf16* __restrict__ A, const bf16* __restrict__ Bt,
    const float* __restrict__ bias,
    bf16* __restrict__ q, bf16* __restrict__ k, bf16* __restrict__ v)
{
  __shared__ __align__(16) bf16 lds[24576];   // A[2][4096] | B[2][8192] = 48KB
  int lin = blockIdx.x;
  int xcd = lin & 7, s = lin >> 3;
  int by = xcd * 8 + (s & 7);        // 64 row-blocks = 8 XCD x 8 (A-panel L2 affinity)
  int bx = s >> 3;                   // 12 col-blocks
  int m0 = by * 128, n0 = bx * 256;
  int t = threadIdx.x;
  int wid = t >> 6, lane = t & 63;
  int l15 = lane & 15, quad = lane >> 4;
  int wc = wid;                      // wave tile: all 128 rows x cols wc*64..

  const bf16* Ag = A + (long)m0 * EMB;
  const bf16* Bg = Bt + (long)n0 * EMB;

  f32x4 acc[8][4] = {};
  bf16x8 af[8], bfr[4];
  constexpr int NT = EMB / 32;       // 32 K-tiles
  // physical chunk slot for all frag reads (rotation swizzle; see header)
  int ph8 = ((quad + (l15 >> 1)) & 3) * 8;

#define LDSA(b) (lds + (b) * 4096)
#define LDSB(b) (lds + 8192 + (b) * 8192)

  // stage a 64-row x 32-col quarter: 1 gload_lds per thread (4KB).
  // LDS dest linear; slot p=t&3 receives logical chunk (p-(r>>1))&3.
#define ISSUE64(gbase, rowoff, ldst, ktt)                                      \
  { int r_ = (rowoff) + (t >> 2);                                              \
    int g_ = ((t & 3) - ((t >> 3) & 3)) & 3;                                   \
    ld_lds16(&(gbase)[(long)r_ * EMB + (ktt) + g_ * 8],                        \
             (ldst) + ((rowoff) + wid * 16) * 32); }

#define RD_A(mi) { int r_ = (mi) * 16 + l15;                                   \
    af[mi] = *(const bf16x8*)&Ab[r_ * 32 + ph8]; }
#define RD_B(ni) { int r_ = wc * 64 + (ni) * 16 + l15;                         \
    bfr[ni] = *(const bf16x8*)&Bb[r_ * 32 + ph8]; }

#define FENCE asm volatile("" ::: "memory")
#define BAR   { FENCE; __builtin_amdgcn_s_barrier(); FENCE; }

#define MFMAC(nlo)                                                             \
  { __builtin_amdgcn_s_setprio(1);                                             \
    _Pragma("unroll") for (int mi_ = 0; mi_ < 8; ++mi_)                        \
      _Pragma("unroll") for (int nj_ = 0; nj_ < 2; ++nj_)                      \
        acc[mi_][(nlo) + nj_] = __builtin_amdgcn_mfma_f32_16x16x32_bf16(       \
            af[mi_], bfr[(nlo) + nj_], acc[mi_][(nlo) + nj_], 0, 0, 0);        \
    __builtin_amdgcn_s_setprio(0); }

  // prologue: tile0 complete (6 issues) + A0(tile1) in flight
  ISSUE64(Ag, 0,   LDSA(0), 0);
  ISSUE64(Ag, 64,  LDSA(0), 0);
  ISSUE64(Bg, 0,   LDSB(0), 0);
  ISSUE64(Bg, 64,  LDSB(0), 0);
  ISSUE64(Bg, 128, LDSB(0), 0);
  ISSUE64(Bg, 192, LDSB(0), 0);
  ISSUE64(Ag, 0,   LDSA(1), 32);
  asm volatile("s_waitcnt vmcnt(1)" ::: "memory");
  BAR;

#pragma unroll 2
  for (int tt = 0; tt < NT; ++tt) {
    const bf16* Ab = LDSA(tt & 1);
    const bf16* Bb = LDSB(tt & 1);
    bf16* An = LDSA((tt + 1) & 1);
    bf16* Bn = LDSB((tt + 1) & 1);
    bf16* Ac = LDSA(tt & 1);                         // A0(t+2): (tt+2)&1==tt&1
    int kn  = (tt + 1 < NT ? tt + 1 : NT - 1) * 32;  // clamped at tail:
    int kn2 = (tt + 2 < NT ? tt + 2 : NT - 1) * 32;  // dummy identical reload

    // P0: all A frags + low B frags; prefetch A1/B0/B1/B2(t+1)
#pragma unroll
    for (int mi = 0; mi < 8; ++mi) RD_A(mi);
    RD_B(0); RD_B(1);
    ISSUE64(Ag, 64,  An, kn);
    ISSUE64(Bg, 0,   Bn, kn);
    ISSUE64(Bg, 64,  Bn, kn);
    ISSUE64(Bg, 128, Bn, kn);
    BAR; MFMAC(0); BAR;
    // P1: high B frags; prefetch B3(t+1) + A0(t+2) (A reads done in P0)
    RD_B(2); RD_B(3);
    ISSUE64(Bg, 192, Bn, kn);
    ISSUE64(Ag, 0,   Ac, kn2);
    asm volatile("s_waitcnt vmcnt(1)" ::: "memory");  // t+1 fully landed
    BAR; MFMAC(2); BAR;
  }

  asm volatile("s_waitcnt vmcnt(0)" ::: "memory");   // drain clamped DMAs
  __syncthreads();

  // ---------------- epilogue: Q (scaled) / K / V^T scatter ----------------
  int which = bx >> 2;   // tile lies entirely in Q, K, or V
  if (which < 2) {
    bf16* dst = (which == 0) ? q : k;
    float scale = (which == 0) ? QSCALE : 1.0f;
#pragma unroll
    for (int mi = 0; mi < 8; ++mi)
#pragma unroll
      for (int ni = 0; ni < 4; ++ni) {
        int gcol = n0 + wc * 64 + ni * 16 + l15;
        float bv = bias[gcol];
        int e = gcol & 1023, h = e >> 6, d = e & 63;
#pragma unroll
        for (int i = 0; i < 4; ++i) {
          int grow = m0 + mi * 16 + quad * 4 + i;
          int b = grow >> 11, ss = grow & 2047;
          dst[(((long)b * NH + h) * SEQ + ss) * HD + d] =
              (bf16)((acc[mi][ni][i] + bv) * scale);
        }
      }
  } else {
    // V^T scatter (proven: WRITE_SIZE stays ideal, L2 absorbs)
#pragma unroll
    for (int mi = 0; mi < 8; ++mi)
#pragma unroll
      for (int ni = 0; ni < 4; ++ni) {
        int gcol = n0 + wc * 64 + ni * 16 + l15;
        float bv = bias[gcol];
        int e = gcol & 1023, h = e >> 6, d = e & 63;
#pragma unroll
        for (int i = 0; i < 4; ++i) {
          int grow = m0 + mi * 16 + quad * 4 + i;
          int b = grow >> 11, ss = grow & 2047;
          v[(((long)b * NH + h) * HD + d) * SEQ + ss] =
              (bf16)(acc[mi][ni][i] + bv);
        }
      }
  }
#undef LDSA
#undef LDSB
#undef ISSUE64
#undef RD_A
#undef RD_B
#undef MFMAC
}

// ---------------- proj GEMM (R0 known-good): 128x64 tile, 3 blocks/CU ------
__global__ __launch_bounds__(256, 3) void gemm_proj(
    const bf16* __restrict__ A, const bf16* __restrict__ Bt,
    const float* __restrict__ bias, float* __restrict__ out)
{
  __shared__ __align__(16) bf16 Al[128 * 64];
  __shared__ __align__(16) bf16 Bl[64 * 64];
  int lin = blockIdx.x;
  int xcd = lin & 7, s = lin >> 3;
  int bx = s >> 3, by = xcd * 8 + (s & 7);
  int m0 = by * 128;
  int n0 = bx * 64;
  int t = threadIdx.x;
  int wave = t >> 6, lane = t & 63;
  int l15 = lane & 15, quad = lane >> 4;
  int wm = (wave & 1) * 64, wn = (wave >> 1) * 32;

  f32x4 acc[4][2] = {};

  for (int kt = 0; kt < EMB; kt += 64) {
    __syncthreads();
#pragma unroll
    for (int it = 0; it < 4; ++it) {         // A: 128 rows x 8 units
      int c = it * 256 + t;
      int row = c >> 3, u = c & 7;
      ld_lds16(&A[(long)(m0 + row) * EMB + kt + ((u ^ (row & 7)) * 8)],
               &Al[(it * 256 + wave * 64) * 8]);
    }
    {
      int c = t;                              // B: 64 rows x 8 units
      int row = c >> 3, u = c & 7;
      ld_lds16(&Bt[(long)(n0 + row) * EMB + kt + ((u ^ (row & 7)) * 8)],
               &Bl[(wave * 64) * 8]);
      c = 256 + t;
      row = c >> 3; u = c & 7;
      ld_lds16(&Bt[(long)(n0 + row) * EMB + kt + ((u ^ (row & 7)) * 8)],
               &Bl[(256 + wave * 64) * 8]);
    }
    __syncthreads();
#pragma unroll
    for (int ks = 0; ks < 2; ++ks) {
      bf16x8 af[4], bfr[2];
#pragma unroll
      for (int i = 0; i < 4; ++i) {
        int r = wm + i * 16 + l15;
        af[i] = *(const bf16x8*)(&Al[r * 64 + (((ks * 4 + quad) ^ (r & 7)) * 8)]);
      }
#pragma unroll
      for (int i = 0; i < 2; ++i) {
        int r = wn + i * 16 + l15;
        bfr[i] = *(const bf16x8*)(&Bl[r * 64 + (((ks * 4 + quad) ^ (r & 7)) * 8)]);
      }
#pragma unroll
      for (int mi = 0; mi < 4; ++mi)
#pragma unroll
        for (int ni = 0; ni < 2; ++ni)
          acc[mi][ni] = __builtin_amdgcn_mfma_f32_16x16x32_bf16(af[mi], bfr[ni], acc[mi][ni], 0, 0, 0);
    }
  }

#pragma unroll
  for (int mi = 0; mi < 4; ++mi)
#pragma unroll
    for (int ni = 0; ni < 2; ++ni) {
      int gcol = n0 + wn + ni * 16 + l15;
      float bv = bias[gcol];
#pragma unroll
      for (int i = 0; i < 4; ++i) {
        int grow = m0 + wm + mi * 16 + quad * 4 + i;
        out[(long)grow * EMB + gcol] = acc[mi][ni][i] + bv;
      }
    }
}

// ---------------- flash attention ----------------
// 1D grid 512 blocks; block 256 = 4 waves x 32 q-rows = 128-row strip.
// Decode: xcd=L&7, a=L>>3; head = xcd + 8*(a&7)  -> all 8 blocks of a head
// share L%8 (same XCD under round-robin dispatch; per-XCD L2 holds the head's
// 512 KB K/V). strip = a>>3; block runs strips st and 15-st (18 tiles each).
// 64-key tiles staged ONCE per block (shared by 4 waves) via global_load_lds.
#define LDP 72   // P row stride (elems): conflict-free, 16B-aligned

__global__ __launch_bounds__(256, 2) void attn(
    const bf16* __restrict__ Q, const bf16* __restrict__ K,
    const bf16* __restrict__ Vt, bf16* __restrict__ Y)
{
  __shared__ __align__(16) bf16 Kl[64 * 64];        // 8 KB
  __shared__ __align__(16) bf16 Vl[64 * 64];        // 8 KB
  __shared__ __align__(16) bf16 Pl[4][32 * LDP];    // 18 KB, per-wave
  int L = blockIdx.x;
  int a = L >> 3;
  int hd = (L & 7) + 8 * (a & 7);
  int st = a >> 3;
  int b = hd >> 4, h = hd & 15;
  const bf16* Qp  = Q  + (((long)b * NH + h) * SEQ) * HD;
  const bf16* Kp  = K  + (((long)b * NH + h) * SEQ) * HD;
  const bf16* Vtp = Vt + (((long)b * NH + h) * HD) * SEQ;
  int t = threadIdx.x, wave = t >> 6, lane = t & 63;
  int l15 = lane & 15, quad = lane >> 4;

#pragma unroll 1
  for (int pass = 0; pass < 2; ++pass) {
    int q0 = (pass == 0) ? st * 128 : (SEQ - 128) - st * 128;
    int wq0 = q0 + wave * 32;

    // Q fragments: m-frag m covers rows wq0+m*16 .. +15; k split 0/32
    bf16x8 qf[2][2];
#pragma unroll
    for (int m = 0; m < 2; ++m) {
      const bf16* qrow = Qp + (long)(wq0 + m * 16 + l15) * HD + quad * 8;
      qf[m][0] = *(const bf16x8*)(qrow);
      qf[m][1] = *(const bf16x8*)(qrow + 32);
    }
    float lrow[2][4] = {};
    f32x4 oacc[2][4] = {};

    int ntiles = q0 / 64 + 2;     // block's 128 rows need tiles through q0+127
#pragma unroll 1
    for (int kt = 0; kt < ntiles; ++kt) {
      int k0 = kt * 64;
      __syncthreads();
      // stage K [key][d], V^T [d][key]: unit row*8+u holds chunk u^(row&7)
#pragma unroll
      for (int it = 0; it < 2; ++it) {
        int cu = it * 256 + t;
        int row = cu >> 3, u = cu & 7;
        ld_lds16(&Kp[(long)(k0 + row) * HD + ((u ^ (row & 7)) * 8)],
                 &Kl[(it * 256 + wave * 64) * 8]);
        ld_lds16(&Vtp[(long)row * SEQ + k0 + ((u ^ (row & 7)) * 8)],
                 &Vl[(it * 256 + wave * 64) * 8]);
      }
      __syncthreads();
      if (k0 > wq0 + 31) continue;   // wave's rows all masked for this tile

      // scores: S[32q x 64k]; kfr register-shared across both m-frags
      f32x4 sc[2][4] = {};
#pragma unroll
      for (int kk = 0; kk < 2; ++kk) {
#pragma unroll
        for (int ni = 0; ni < 4; ++ni) {
          int r = ni * 16 + l15, u = kk * 4 + quad;
          bf16x8 kfr = *(const bf16x8*)(&Kl[r * 64 + ((u ^ (r & 7)) * 8)]);
          sc[0][ni] = __builtin_amdgcn_mfma_f32_16x16x32_bf16(qf[0][kk], kfr, sc[0][ni], 0, 0, 0);
          sc[1][ni] = __builtin_amdgcn_mfma_f32_16x16x32_bf16(qf[1][kk], kfr, sc[1][ni], 0, 0, 0);
        }
      }

      bool full = (k0 + 63 <= wq0);   // wave-uniform (min row = wq0)
#pragma unroll
      for (int m = 0; m < 2; ++m) {
#pragma unroll
        for (int i = 0; i < 4; ++i) {
          int qr = wq0 + m * 16 + quad * 4 + i;
          float e[4];
#pragma unroll
          for (int ni = 0; ni < 4; ++ni) {
            float x = sc[m][ni][i];
            if (!full) x = (k0 + ni * 16 + l15 <= qr) ? x : -1e30f;
            e[ni] = __builtin_amdgcn_exp2f(x);
          }
          lrow[m][i] += (e[0] + e[1]) + (e[2] + e[3]);
          int prow = (m * 16 + quad * 4 + i) * LDP;
#pragma unroll
          for (int ni = 0; ni < 4; ++ni)
            Pl[wave][prow + ni * 16 + l15] = (bf16)e[ni];
        }
      }
      asm volatile("s_waitcnt lgkmcnt(0)" ::: "memory");
      // PV: P[32x64] @ V[64x64]; vf register-shared across both m-frags
#pragma unroll
      for (int kk = 0; kk < 2; ++kk) {
        int kbase = kk * 32 + quad * 8;
        bf16x8 pf0 = *(const bf16x8*)(&Pl[wave][(l15) * LDP + kbase]);
        bf16x8 pf1 = *(const bf16x8*)(&Pl[wave][(16 + l15) * LDP + kbase]);
#pragma unroll
        for (int ni = 0; ni < 4; ++ni) {
          int dd = ni * 16 + l15, u = kk * 4 + quad;
          bf16x8 vf = *(const bf16x8*)(&Vl[dd * 64 + ((u ^ (dd & 7)) * 8)]);
          oacc[0][ni] = __builtin_amdgcn_mfma_f32_16x16x32_bf16(pf0, vf, oacc[0][ni], 0, 0, 0);
          oacc[1][ni] = __builtin_amdgcn_mfma_f32_16x16x32_bf16(pf1, vf, oacc[1][ni], 0, 0, 0);
        }
      }
    }
    // epilogue: reduce l across the 16-lane column groups, write Y bf16
#pragma unroll
    for (int m = 0; m < 2; ++m) {
#pragma unroll
      for (int i = 0; i < 4; ++i) {
        float rs = lrow[m][i];
#pragma unroll
        for (int off = 8; off; off >>= 1) rs += __shfl_xor(rs, off, 16);
        float inv = 1.0f / rs;
        int qr = wq0 + m * 16 + quad * 4 + i;
        bf16* dst = Y + ((long)(b * SEQ + qr)) * EMB + h * HD;
#pragma unroll
        for (int ni = 0; ni < 4; ++ni)
          dst[ni * 16 + l15] = (bf16)(oacc[m][ni][i] * inv);
      }
    }
  }
}

extern "C" void kernel_launch(void* const* d_in, const int* in_sizes, int n_in,
                              void* d_out, int out_size, void* d_ws, size_t ws_size,
                              hipStream_t stream) {
  const float* x      = (const float*)d_in[0];
  const float* W_attn = (const float*)d_in[1];
  const float* b_attn = (const float*)d_in[2];
  const float* W_proj = (const float*)d_in[3];
  const float* b_proj = (const float*)d_in[4];
  float* out = (float*)d_out;
  char* ws = (char*)d_ws;
  bf16* xb  = (bf16*)(ws);                 // 16.78 MB
  bf16* WaT = (bf16*)(ws + 16777216);      //  6.29 MB
  bf16* WpT = (bf16*)(ws + 23068672);      //  2.10 MB
  bf16* Qb  = (bf16*)(ws + 25165824);      // 16.78 MB (pre-scaled)
  bf16* Kb  = (bf16*)(ws + 41943040);      // 16.78 MB
  bf16* Vtb = (bf16*)(ws + 58720256);      // 16.78 MB (transposed [b,h,d,s])
  bf16* Yb  = (bf16*)(ws + 75497472);      // 16.78 MB

  cvt_f32_bf16<<<8192, 256, 0, stream>>>(x, xb, BATCH * SEQ * EMB);
  transpose_cvt2<<<dim3(128, 32), 256, 0, stream>>>(W_attn, W_proj, WaT, WpT);
  gemm8p<<<768, 256, 0, stream>>>(xb, WaT, b_attn, Qb, Kb, Vtb);
  attn<<<512, 256, 0, stream>>>(Qb, Kb, Vtb, Yb);
  gemm_proj<<<1024, 256, 0, stream>>>(Yb, WpT, b_proj, out);
}

// Round 6
// 262.830 us; speedup vs baseline: 1.5083x; 1.5083x over previous
//
#include <hip/hip_runtime.h>

// CausalSelfAttention: x[4,2048,1024] fp32 -> out fp32
// Pipeline (all bf16 MFMA, fp32 accum):
//  1) cvt x -> bf16            2) transpose+cvt W_attn & W_proj -> bf16 [N][K]
//  3) gemm8p (128x256 tile, BK=32, 2-phase/tile counted-vmcnt schedule,
//     768 blocks = 3x256 uniform) -> Q (pre-scaled by 0.125*log2e), K,
//     V TRANSPOSED [b,h,d,s] (scatter)
//  4) flash attention: 128 q-rows/block (4 waves x 32), XCD head-affinity
//     swizzle, fixed-max softmax (P = 2^s), K/Vt direct-to-LDS w/ XOR swizzle.
//  5) gemm_proj (128x64 tile, 1024 blocks, 3/CU) + bias -> out fp32
//
// R6 post-mortem of R5 (396us; gemm8p 215-229us, WRITE_SIZE 557MB, FETCH
// 201MB, MfmaUtil 9.5%):
//   ACCUMULATOR SPILL. launch_bounds(256,3) caps regs at 512/3~170; the
//   per-wave working set is ~196 (acc[8][4]=128 + af[8]=32 + bfr[4]=16 +
//   addr). 196>170 -> spill -> 1.1GB scratch traffic. (The R0 header note
//   documents this exact failure mode; launch_bounds can only CAP regs.)
//   FIX (one line): launch_bounds(256,2) -> cap 256, ~196 fits, no spill.
//   Uniformity needs block COUNT multiple of 256, not 3/CU residency: at
//   2 blocks/CU resident, every CU still executes exactly 3 equal blocks
//   (768=3x256) with full overlap -> makespan 1.5 units/CU vs R4's 2.0.
// Schedule per K-tile (guide T3+T4+T5, counted vmcnt, never 0 in loop):
//   P0 {RD_A x8, RD_B 0-1, issue A1/B0/B1/B2(t+1), BAR, setprio1, 16 MFMA,
//       setprio0, BAR}
//   P1 {RD_B 2-3, issue B3(t+1)/A0(t+2), vmcnt(1), BAR, setprio1, 16 MFMA,
//       setprio0, BAR}
//   steady state: 7 outstanding -> drain to 1: t+1 fully landed, A0(t+2)
//   in flight. Overwrite safety: A reads complete in P0 (consumed by MFMA,
//   lgkmcnt) before P0's trailing barrier; A0(t+2) (same-parity buffer)
//   issued in P1. B(t+1) writes other-parity buffer whose reads finished
//   in tile t-1. Tail issues clamped (identical-data reload).
// Rotation swizzle (conflict-free, verified R3): writer puts logical chunk
//   ((t&3)-((t>>3)&3))&3 in slot t&3; reader slot (quad+(l15>>1))&3.
//   Bank-quad covers all 8 quads 2x over 16 lanes -> 2-way = free (m136).
// MFMA 16x16x32 bf16 layouts (HW-verified per guide):
//   A: a[j] = A[m=lane&15][k=quad*8+j]  (quad=lane>>4)
//   B: b[j] = B[k=quad*8+j][n=lane&15]  (from Bt[n][k] read at row n)
//   C/D: c[i] = D[row=quad*4+i][col=lane&15]

#define BATCH 4
#define SEQ   2048
#define EMB   1024
#define NH    16
#define HD    64

typedef __bf16 bf16;
typedef __bf16 bf16x8 __attribute__((ext_vector_type(8)));
typedef float  f32x4  __attribute__((ext_vector_type(4)));

// direct global->LDS 16B copy: LDS dest is wave-uniform base + lane*16
__device__ __forceinline__ void ld_lds16(const void* g, void* l) {
  __builtin_amdgcn_global_load_lds(
      (const __attribute__((address_space(1))) void*)g,
      (__attribute__((address_space(3))) void*)l, 16, 0, 0);
}

// ---------------- convert fp32 -> bf16 ----------------
__global__ void cvt_f32_bf16(const float* __restrict__ in, bf16* __restrict__ out, int n) {
  int i = (blockIdx.x * blockDim.x + threadIdx.x) * 4;
  if (i + 3 < n) {
    float4 v = *(const float4*)(in + i);
    bf16 o0 = (bf16)v.x, o1 = (bf16)v.y, o2 = (bf16)v.z, o3 = (bf16)v.w;
    out[i] = o0; out[i+1] = o1; out[i+2] = o2; out[i+3] = o3;
  }
}

// ---------------- transpose + convert both weights (one launch) ----------------
__global__ void transpose_cvt2(const float* __restrict__ Wa, const float* __restrict__ Wp,
                               bf16* __restrict__ WaT, bf16* __restrict__ WpT) {
  __shared__ float tile[32][33];
  int bx = blockIdx.x;
  const float* W; bf16* WT; int N;
  if (bx < 96) { W = Wa; WT = WaT; N = 3072; }
  else         { W = Wp; WT = WpT; N = 1024; bx -= 96; }
  int n0 = bx * 32, k0 = blockIdx.y * 32;
  int tx = threadIdx.x & 31, ty = threadIdx.x >> 5;
#pragma unroll
  for (int r = 0; r < 4; r++) {
    int k = k0 + ty + r * 8;
    tile[ty + r * 8][tx] = W[(long)k * N + n0 + tx];
  }
  __syncthreads();
#pragma unroll
  for (int r = 0; r < 4; r++) {
    int n = n0 + ty + r * 8;
    WT[(long)n * EMB + k0 + tx] = (bf16)tile[tx][ty + r * 8];
  }
}

#define QSCALE 0.18033688f   // (1/8) * log2(e)

// ---------------- 128x256 phase-pipelined QKV GEMM ----------------
// A[8192][1024] bf16 x Bt[3072][1024] bf16 + bias -> Q/K/V.
// Grid 768 (=3x256 uniform) x 256 thr (4 waves, 1Mx4N).
__global__ __launch_bounds__(256, 2) void gemm8p(
    const bf16* __restrict__ A, const bf16* __restrict__ Bt,
    const float* __restrict__ bias,
    bf16* __restrict__ q, bf16* __restrict__ k, bf16* __restrict__ v)
{
  __shared__ __align__(16) bf16 lds[24576];   // A[2][4096] | B[2][8192] = 48KB
  int lin = blockIdx.x;
  int xcd = lin & 7, s = lin >> 3;
  int by = xcd * 8 + (s & 7);        // 64 row-blocks = 8 XCD x 8 (A-panel L2 affinity)
  int bx = s >> 3;                   // 12 col-blocks
  int m0 = by * 128, n0 = bx * 256;
  int t = threadIdx.x;
  int wid = t >> 6, lane = t & 63;
  int l15 = lane & 15, quad = lane >> 4;
  int wc = wid;                      // wave tile: all 128 rows x cols wc*64..

  const bf16* Ag = A + (long)m0 * EMB;
  const bf16* Bg = Bt + (long)n0 * EMB;

  f32x4 acc[8][4] = {};
  bf16x8 af[8], bfr[4];
  constexpr int NT = EMB / 32;       // 32 K-tiles
  // physical chunk slot for all frag reads (rotation swizzle; see header)
  int ph8 = ((quad + (l15 >> 1)) & 3) * 8;

#define LDSA(b) (lds + (b) * 4096)
#define LDSB(b) (lds + 8192 + (b) * 8192)

  // stage a 64-row x 32-col quarter: 1 gload_lds per thread (4KB).
  // LDS dest linear; slot p=t&3 receives logical chunk (p-(r>>1))&3.
#define ISSUE64(gbase, rowoff, ldst, ktt)                                      \
  { int r_ = (rowoff) + (t >> 2);                                              \
    int g_ = ((t & 3) - ((t >> 3) & 3)) & 3;                                   \
    ld_lds16(&(gbase)[(long)r_ * EMB + (ktt) + g_ * 8],                        \
             (ldst) + ((rowoff) + wid * 16) * 32); }

#define RD_A(mi) { int r_ = (mi) * 16 + l15;                                   \
    af[mi] = *(const bf16x8*)&Ab[r_ * 32 + ph8]; }
#define RD_B(ni) { int r_ = wc * 64 + (ni) * 16 + l15;                         \
    bfr[ni] = *(const bf16x8*)&Bb[r_ * 32 + ph8]; }

#define FENCE asm volatile("" ::: "memory")
#define BAR   { FENCE; __builtin_amdgcn_s_barrier(); FENCE; }

#define MFMAC(nlo)                                                             \
  { __builtin_amdgcn_s_setprio(1);                                             \
    _Pragma("unroll") for (int mi_ = 0; mi_ < 8; ++mi_)                        \
      _Pragma("unroll") for (int nj_ = 0; nj_ < 2; ++nj_)                      \
        acc[mi_][(nlo) + nj_] = __builtin_amdgcn_mfma_f32_16x16x32_bf16(       \
            af[mi_], bfr[(nlo) + nj_], acc[mi_][(nlo) + nj_], 0, 0, 0);        \
    __builtin_amdgcn_s_setprio(0); }

  // prologue: tile0 complete (6 issues) + A0(tile1) in flight
  ISSUE64(Ag, 0,   LDSA(0), 0);
  ISSUE64(Ag, 64,  LDSA(0), 0);
  ISSUE64(Bg, 0,   LDSB(0), 0);
  ISSUE64(Bg, 64,  LDSB(0), 0);
  ISSUE64(Bg, 128, LDSB(0), 0);
  ISSUE64(Bg, 192, LDSB(0), 0);
  ISSUE64(Ag, 0,   LDSA(1), 32);
  asm volatile("s_waitcnt vmcnt(1)" ::: "memory");
  BAR;

#pragma unroll 2
  for (int tt = 0; tt < NT; ++tt) {
    const bf16* Ab = LDSA(tt & 1);
    const bf16* Bb = LDSB(tt & 1);
    bf16* An = LDSA((tt + 1) & 1);
    bf16* Bn = LDSB((tt + 1) & 1);
    bf16* Ac = LDSA(tt & 1);                         // A0(t+2): (tt+2)&1==tt&1
    int kn  = (tt + 1 < NT ? tt + 1 : NT - 1) * 32;  // clamped at tail:
    int kn2 = (tt + 2 < NT ? tt + 2 : NT - 1) * 32;  // dummy identical reload

    // P0: all A frags + low B frags; prefetch A1/B0/B1/B2(t+1)
#pragma unroll
    for (int mi = 0; mi < 8; ++mi) RD_A(mi);
    RD_B(0); RD_B(1);
    ISSUE64(Ag, 64,  An, kn);
    ISSUE64(Bg, 0,   Bn, kn);
    ISSUE64(Bg, 64,  Bn, kn);
    ISSUE64(Bg, 128, Bn, kn);
    BAR; MFMAC(0); BAR;
    // P1: high B frags; prefetch B3(t+1) + A0(t+2) (A reads done in P0)
    RD_B(2); RD_B(3);
    ISSUE64(Bg, 192, Bn, kn);
    ISSUE64(Ag, 0,   Ac, kn2);
    asm volatile("s_waitcnt vmcnt(1)" ::: "memory");  // t+1 fully landed
    BAR; MFMAC(2); BAR;
  }

  asm volatile("s_waitcnt vmcnt(0)" ::: "memory");   // drain clamped DMAs
  __syncthreads();

  // ---------------- epilogue: Q (scaled) / K / V^T scatter ----------------
  int which = bx >> 2;   // tile lies entirely in Q, K, or V
  if (which < 2) {
    bf16* dst = (which == 0) ? q : k;
    float scale = (which == 0) ? QSCALE : 1.0f;
#pragma unroll
    for (int mi = 0; mi < 8; ++mi)
#pragma unroll
      for (int ni = 0; ni < 4; ++ni) {
        int gcol = n0 + wc * 64 + ni * 16 + l15;
        float bv = bias[gcol];
        int e = gcol & 1023, h = e >> 6, d = e & 63;
#pragma unroll
        for (int i = 0; i < 4; ++i) {
          int grow = m0 + mi * 16 + quad * 4 + i;
          int b = grow >> 11, ss = grow & 2047;
          dst[(((long)b * NH + h) * SEQ + ss) * HD + d] =
              (bf16)((acc[mi][ni][i] + bv) * scale);
        }
      }
  } else {
    // V^T scatter (proven: WRITE_SIZE stays ideal, L2 absorbs)
#pragma unroll
    for (int mi = 0; mi < 8; ++mi)
#pragma unroll
      for (int ni = 0; ni < 4; ++ni) {
        int gcol = n0 + wc * 64 + ni * 16 + l15;
        float bv = bias[gcol];
        int e = gcol & 1023, h = e >> 6, d = e & 63;
#pragma unroll
        for (int i = 0; i < 4; ++i) {
          int grow = m0 + mi * 16 + quad * 4 + i;
          int b = grow >> 11, ss = grow & 2047;
          v[(((long)b * NH + h) * HD + d) * SEQ + ss] =
              (bf16)(acc[mi][ni][i] + bv);
        }
      }
  }
#undef LDSA
#undef LDSB
#undef ISSUE64
#undef RD_A
#undef RD_B
#undef MFMAC
}

// ---------------- proj GEMM (R0 known-good): 128x64 tile, 3 blocks/CU ------
__global__ __launch_bounds__(256, 3) void gemm_proj(
    const bf16* __restrict__ A, const bf16* __restrict__ Bt,
    const float* __restrict__ bias, float* __restrict__ out)
{
  __shared__ __align__(16) bf16 Al[128 * 64];
  __shared__ __align__(16) bf16 Bl[64 * 64];
  int lin = blockIdx.x;
  int xcd = lin & 7, s = lin >> 3;
  int bx = s >> 3, by = xcd * 8 + (s & 7);
  int m0 = by * 128;
  int n0 = bx * 64;
  int t = threadIdx.x;
  int wave = t >> 6, lane = t & 63;
  int l15 = lane & 15, quad = lane >> 4;
  int wm = (wave & 1) * 64, wn = (wave >> 1) * 32;

  f32x4 acc[4][2] = {};

  for (int kt = 0; kt < EMB; kt += 64) {
    __syncthreads();
#pragma unroll
    for (int it = 0; it < 4; ++it) {         // A: 128 rows x 8 units
      int c = it * 256 + t;
      int row = c >> 3, u = c & 7;
      ld_lds16(&A[(long)(m0 + row) * EMB + kt + ((u ^ (row & 7)) * 8)],
               &Al[(it * 256 + wave * 64) * 8]);
    }
    {
      int c = t;                              // B: 64 rows x 8 units
      int row = c >> 3, u = c & 7;
      ld_lds16(&Bt[(long)(n0 + row) * EMB + kt + ((u ^ (row & 7)) * 8)],
               &Bl[(wave * 64) * 8]);
      c = 256 + t;
      row = c >> 3; u = c & 7;
      ld_lds16(&Bt[(long)(n0 + row) * EMB + kt + ((u ^ (row & 7)) * 8)],
               &Bl[(256 + wave * 64) * 8]);
    }
    __syncthreads();
#pragma unroll
    for (int ks = 0; ks < 2; ++ks) {
      bf16x8 af[4], bfr[2];
#pragma unroll
      for (int i = 0; i < 4; ++i) {
        int r = wm + i * 16 + l15;
        af[i] = *(const bf16x8*)(&Al[r * 64 + (((ks * 4 + quad) ^ (r & 7)) * 8)]);
      }
#pragma unroll
      for (int i = 0; i < 2; ++i) {
        int r = wn + i * 16 + l15;
        bfr[i] = *(const bf16x8*)(&Bl[r * 64 + (((ks * 4 + quad) ^ (r & 7)) * 8)]);
      }
#pragma unroll
      for (int mi = 0; mi < 4; ++mi)
#pragma unroll
        for (int ni = 0; ni < 2; ++ni)
          acc[mi][ni] = __builtin_amdgcn_mfma_f32_16x16x32_bf16(af[mi], bfr[ni], acc[mi][ni], 0, 0, 0);
    }
  }

#pragma unroll
  for (int mi = 0; mi < 4; ++mi)
#pragma unroll
    for (int ni = 0; ni < 2; ++ni) {
      int gcol = n0 + wn + ni * 16 + l15;
      float bv = bias[gcol];
#pragma unroll
      for (int i = 0; i < 4; ++i) {
        int grow = m0 + wm + mi * 16 + quad * 4 + i;
        out[(long)grow * EMB + gcol] = acc[mi][ni][i] + bv;
      }
    }
}

// ---------------- flash attention ----------------
// 1D grid 512 blocks; block 256 = 4 waves x 32 q-rows = 128-row strip.
// Decode: xcd=L&7, a=L>>3; head = xcd + 8*(a&7)  -> all 8 blocks of a head
// share L%8 (same XCD under round-robin dispatch; per-XCD L2 holds the head's
// 512 KB K/V). strip = a>>3; block runs strips st and 15-st (18 tiles each).
// 64-key tiles staged ONCE per block (shared by 4 waves) via global_load_lds.
#define LDP 72   // P row stride (elems): conflict-free, 16B-aligned

__global__ __launch_bounds__(256, 2) void attn(
    const bf16* __restrict__ Q, const bf16* __restrict__ K,
    const bf16* __restrict__ Vt, bf16* __restrict__ Y)
{
  __shared__ __align__(16) bf16 Kl[64 * 64];        // 8 KB
  __shared__ __align__(16) bf16 Vl[64 * 64];        // 8 KB
  __shared__ __align__(16) bf16 Pl[4][32 * LDP];    // 18 KB, per-wave
  int L = blockIdx.x;
  int a = L >> 3;
  int hd = (L & 7) + 8 * (a & 7);
  int st = a >> 3;
  int b = hd >> 4, h = hd & 15;
  const bf16* Qp  = Q  + (((long)b * NH + h) * SEQ) * HD;
  const bf16* Kp  = K  + (((long)b * NH + h) * SEQ) * HD;
  const bf16* Vtp = Vt + (((long)b * NH + h) * HD) * SEQ;
  int t = threadIdx.x, wave = t >> 6, lane = t & 63;
  int l15 = lane & 15, quad = lane >> 4;

#pragma unroll 1
  for (int pass = 0; pass < 2; ++pass) {
    int q0 = (pass == 0) ? st * 128 : (SEQ - 128) - st * 128;
    int wq0 = q0 + wave * 32;

    // Q fragments: m-frag m covers rows wq0+m*16 .. +15; k split 0/32
    bf16x8 qf[2][2];
#pragma unroll
    for (int m = 0; m < 2; ++m) {
      const bf16* qrow = Qp + (long)(wq0 + m * 16 + l15) * HD + quad * 8;
      qf[m][0] = *(const bf16x8*)(qrow);
      qf[m][1] = *(const bf16x8*)(qrow + 32);
    }
    float lrow[2][4] = {};
    f32x4 oacc[2][4] = {};

    int ntiles = q0 / 64 + 2;     // block's 128 rows need tiles through q0+127
#pragma unroll 1
    for (int kt = 0; kt < ntiles; ++kt) {
      int k0 = kt * 64;
      __syncthreads();
      // stage K [key][d], V^T [d][key]: unit row*8+u holds chunk u^(row&7)
#pragma unroll
      for (int it = 0; it < 2; ++it) {
        int cu = it * 256 + t;
        int row = cu >> 3, u = cu & 7;
        ld_lds16(&Kp[(long)(k0 + row) * HD + ((u ^ (row & 7)) * 8)],
                 &Kl[(it * 256 + wave * 64) * 8]);
        ld_lds16(&Vtp[(long)row * SEQ + k0 + ((u ^ (row & 7)) * 8)],
                 &Vl[(it * 256 + wave * 64) * 8]);
      }
      __syncthreads();
      if (k0 > wq0 + 31) continue;   // wave's rows all masked for this tile

      // scores: S[32q x 64k]; kfr register-shared across both m-frags
      f32x4 sc[2][4] = {};
#pragma unroll
      for (int kk = 0; kk < 2; ++kk) {
#pragma unroll
        for (int ni = 0; ni < 4; ++ni) {
          int r = ni * 16 + l15, u = kk * 4 + quad;
          bf16x8 kfr = *(const bf16x8*)(&Kl[r * 64 + ((u ^ (r & 7)) * 8)]);
          sc[0][ni] = __builtin_amdgcn_mfma_f32_16x16x32_bf16(qf[0][kk], kfr, sc[0][ni], 0, 0, 0);
          sc[1][ni] = __builtin_amdgcn_mfma_f32_16x16x32_bf16(qf[1][kk], kfr, sc[1][ni], 0, 0, 0);
        }
      }

      bool full = (k0 + 63 <= wq0);   // wave-uniform (min row = wq0)
#pragma unroll
      for (int m = 0; m < 2; ++m) {
#pragma unroll
        for (int i = 0; i < 4; ++i) {
          int qr = wq0 + m * 16 + quad * 4 + i;
          float e[4];
#pragma unroll
          for (int ni = 0; ni < 4; ++ni) {
            float x = sc[m][ni][i];
            if (!full) x = (k0 + ni * 16 + l15 <= qr) ? x : -1e30f;
            e[ni] = __builtin_amdgcn_exp2f(x);
          }
          lrow[m][i] += (e[0] + e[1]) + (e[2] + e[3]);
          int prow = (m * 16 + quad * 4 + i) * LDP;
#pragma unroll
          for (int ni = 0; ni < 4; ++ni)
            Pl[wave][prow + ni * 16 + l15] = (bf16)e[ni];
        }
      }
      asm volatile("s_waitcnt lgkmcnt(0)" ::: "memory");
      // PV: P[32x64] @ V[64x64]; vf register-shared across both m-frags
#pragma unroll
      for (int kk = 0; kk < 2; ++kk) {
        int kbase = kk * 32 + quad * 8;
        bf16x8 pf0 = *(const bf16x8*)(&Pl[wave][(l15) * LDP + kbase]);
        bf16x8 pf1 = *(const bf16x8*)(&Pl[wave][(16 + l15) * LDP + kbase]);
#pragma unroll
        for (int ni = 0; ni < 4; ++ni) {
          int dd = ni * 16 + l15, u = kk * 4 + quad;
          bf16x8 vf = *(const bf16x8*)(&Vl[dd * 64 + ((u ^ (dd & 7)) * 8)]);
          oacc[0][ni] = __builtin_amdgcn_mfma_f32_16x16x32_bf16(pf0, vf, oacc[0][ni], 0, 0, 0);
          oacc[1][ni] = __builtin_amdgcn_mfma_f32_16x16x32_bf16(pf1, vf, oacc[1][ni], 0, 0, 0);
        }
      }
    }
    // epilogue: reduce l across the 16-lane column groups, write Y bf16
#pragma unroll
    for (int m = 0; m < 2; ++m) {
#pragma unroll
      for (int i = 0; i < 4; ++i) {
        float rs = lrow[m][i];
#pragma unroll
        for (int off = 8; off; off >>= 1) rs += __shfl_xor(rs, off, 16);
        float inv = 1.0f / rs;
        int qr = wq0 + m * 16 + quad * 4 + i;
        bf16* dst = Y + ((long)(b * SEQ + qr)) * EMB + h * HD;
#pragma unroll
        for (int ni = 0; ni < 4; ++ni)
          dst[ni * 16 + l15] = (bf16)(oacc[m][ni][i] * inv);
      }
    }
  }
}

extern "C" void kernel_launch(void* const* d_in, const int* in_sizes, int n_in,
                              void* d_out, int out_size, void* d_ws, size_t ws_size,
                              hipStream_t stream) {
  const float* x      = (const float*)d_in[0];
  const float* W_attn = (const float*)d_in[1];
  const float* b_attn = (const float*)d_in[2];
  const float* W_proj = (const float*)d_in[3];
  const float* b_proj = (const float*)d_in[4];
  float* out = (float*)d_out;
  char* ws = (char*)d_ws;
  bf16* xb  = (bf16*)(ws);                 // 16.78 MB
  bf16* WaT = (bf16*)(ws + 16777216);      //  6.29 MB
  bf16* WpT = (bf16*)(ws + 23068672);      //  2.10 MB
  bf16* Qb  = (bf16*)(ws + 25165824);      // 16.78 MB (pre-scaled)
  bf16* Kb  = (bf16*)(ws + 41943040);      // 16.78 MB
  bf16* Vtb = (bf16*)(ws + 58720256);      // 16.78 MB (transposed [b,h,d,s])
  bf16* Yb  = (bf16*)(ws + 75497472);      // 16.78 MB

  cvt_f32_bf16<<<8192, 256, 0, stream>>>(x, xb, BATCH * SEQ * EMB);
  transpose_cvt2<<<dim3(128, 32), 256, 0, stream>>>(W_attn, W_proj, WaT, WpT);
  gemm8p<<<768, 256, 0, stream>>>(xb, WaT, b_attn, Qb, Kb, Vtb);
  attn<<<512, 256, 0, stream>>>(Qb, Kb, Vtb, Yb);
  gemm_proj<<<1024, 256, 0, stream>>>(Yb, WpT, b_proj, out);
}

// Round 7
// 246.692 us; speedup vs baseline: 1.6069x; 1.0654x over previous
//
#include <hip/hip_runtime.h>

// CausalSelfAttention: x[4,2048,1024] fp32 -> out fp32
// Pipeline (all bf16 MFMA, fp32 accum):
//  1) cvt x -> bf16            2) transpose+cvt W_attn & W_proj -> bf16 [N][K]
//  3) gemm8p (128x256 tile, BK=32, 2-phase/tile counted-vmcnt schedule,
//     768 blocks = 3x256 uniform) -> Q (pre-scaled by 0.125*log2e), K,
//     V TRANSPOSED [b,h,d,s] (scatter)
//  4) flash attention: 128 q-rows/block (4 waves x 32), XCD head-affinity
//     swizzle, fixed-max softmax (P = 2^s), K/Vt DOUBLE-BUFFERED direct-to-LDS
//     with counted vmcnt (NEW this round)
//  5) gemm_proj (128x64 tile, 1024 blocks, 3/CU) + bias -> out fp32
//
// R7 post-mortem of R6 (262.8us): top-5 dispatches all attn (76.3us,
// MfmaUtil 18.5%, VALUBusy 37%, HBM 4-7%, FETCH 25MB = L2-resident K/V).
// gemm8p & proj both dropped below attn. attn per-tile arithmetic: compute
// ~250ns (32 MFMA/wave + softmax VALU) vs measured ~1.1us/tile-unit ->
// the serial cost is the stage drain: old loop used __syncthreads() after
// ld_lds16, which emits s_waitcnt vmcnt(0) lgkmcnt(0) -> full global->LDS
// latency exposed on EVERY tile (the same disease the R0 QKV gemm had).
// FIX (proven lever, guide T3+T4): double-buffer K/V; per iteration issue
// tile t+1's 4 DMAs/thread into buf^1, s_waitcnt vmcnt(4) (tile t landed,
// t+1 stays in flight; never 0 except final tile), raw s_barrier (NOT
// __syncthreads - avoids implicit drain), compute from buf, trailing
// barrier. Overwrite safety: buf^1 reads consumed (lgkm before MFMA use)
// before iter t-1's trailing barrier; all waves pass it before t+1's DMAs
// issue. Per-wave masked-tile skip is an if around compute (barriers
// uniform). Per-wave in-order DS covers Pl write-after-read across tiles.
// LDS 34.8 -> 50.4 KB (still >=2 blocks/CU at 512-block grid).
//
// gemm8p schedule (guide T3+T4+T5, counted vmcnt, never 0 in loop):
//   P0 {RD_A x8, RD_B 0-1, issue A1/B0/B1/B2(t+1), BAR, setprio1, 16 MFMA,
//       setprio0, BAR}
//   P1 {RD_B 2-3, issue B3(t+1)/A0(t+2), vmcnt(1), BAR, setprio1, 16 MFMA,
//       setprio0, BAR}
//   launch_bounds(256,2): reg cap 256 >= ~196 working set (R5 lesson:
//   (256,3) caps at ~170 -> accumulator spill -> 557MB WRITE_SIZE).
//   Grid 768 = 3x256: uniform 3 equal blocks per CU (R4 lesson: 384 blocks
//   at 2-cap residency = half the CUs do double work).
// Rotation swizzle (conflict-free, verified R3): writer puts logical chunk
//   ((t&3)-((t>>3)&3))&3 in slot t&3; reader slot (quad+(l15>>1))&3.
// MFMA 16x16x32 bf16 layouts (HW-verified per guide):
//   A: a[j] = A[m=lane&15][k=quad*8+j]  (quad=lane>>4)
//   B: b[j] = B[k=quad*8+j][n=lane&15]  (from Bt[n][k] read at row n)
//   C/D: c[i] = D[row=quad*4+i][col=lane&15]

#define BATCH 4
#define SEQ   2048
#define EMB   1024
#define NH    16
#define HD    64

typedef __bf16 bf16;
typedef __bf16 bf16x8 __attribute__((ext_vector_type(8)));
typedef float  f32x4  __attribute__((ext_vector_type(4)));

// direct global->LDS 16B copy: LDS dest is wave-uniform base + lane*16
__device__ __forceinline__ void ld_lds16(const void* g, void* l) {
  __builtin_amdgcn_global_load_lds(
      (const __attribute__((address_space(1))) void*)g,
      (__attribute__((address_space(3))) void*)l, 16, 0, 0);
}

// ---------------- convert fp32 -> bf16 ----------------
__global__ void cvt_f32_bf16(const float* __restrict__ in, bf16* __restrict__ out, int n) {
  int i = (blockIdx.x * blockDim.x + threadIdx.x) * 4;
  if (i + 3 < n) {
    float4 v = *(const float4*)(in + i);
    bf16 o0 = (bf16)v.x, o1 = (bf16)v.y, o2 = (bf16)v.z, o3 = (bf16)v.w;
    out[i] = o0; out[i+1] = o1; out[i+2] = o2; out[i+3] = o3;
  }
}

// ---------------- transpose + convert both weights (one launch) ----------------
__global__ void transpose_cvt2(const float* __restrict__ Wa, const float* __restrict__ Wp,
                               bf16* __restrict__ WaT, bf16* __restrict__ WpT) {
  __shared__ float tile[32][33];
  int bx = blockIdx.x;
  const float* W; bf16* WT; int N;
  if (bx < 96) { W = Wa; WT = WaT; N = 3072; }
  else         { W = Wp; WT = WpT; N = 1024; bx -= 96; }
  int n0 = bx * 32, k0 = blockIdx.y * 32;
  int tx = threadIdx.x & 31, ty = threadIdx.x >> 5;
#pragma unroll
  for (int r = 0; r < 4; r++) {
    int k = k0 + ty + r * 8;
    tile[ty + r * 8][tx] = W[(long)k * N + n0 + tx];
  }
  __syncthreads();
#pragma unroll
  for (int r = 0; r < 4; r++) {
    int n = n0 + ty + r * 8;
    WT[(long)n * EMB + k0 + tx] = (bf16)tile[tx][ty + r * 8];
  }
}

#define QSCALE 0.18033688f   // (1/8) * log2(e)

// ---------------- 128x256 phase-pipelined QKV GEMM ----------------
// A[8192][1024] bf16 x Bt[3072][1024] bf16 + bias -> Q/K/V.
// Grid 768 (=3x256 uniform) x 256 thr (4 waves, 1Mx4N).
__global__ __launch_bounds__(256, 2) void gemm8p(
    const bf16* __restrict__ A, const bf16* __restrict__ Bt,
    const float* __restrict__ bias,
    bf16* __restrict__ q, bf16* __restrict__ k, bf16* __restrict__ v)
{
  __shared__ __align__(16) bf16 lds[24576];   // A[2][4096] | B[2][8192] = 48KB
  int lin = blockIdx.x;
  int xcd = lin & 7, s = lin >> 3;
  int by = xcd * 8 + (s & 7);        // 64 row-blocks = 8 XCD x 8 (A-panel L2 affinity)
  int bx = s >> 3;                   // 12 col-blocks
  int m0 = by * 128, n0 = bx * 256;
  int t = threadIdx.x;
  int wid = t >> 6, lane = t & 63;
  int l15 = lane & 15, quad = lane >> 4;
  int wc = wid;                      // wave tile: all 128 rows x cols wc*64..

  const bf16* Ag = A + (long)m0 * EMB;
  const bf16* Bg = Bt + (long)n0 * EMB;

  f32x4 acc[8][4] = {};
  bf16x8 af[8], bfr[4];
  constexpr int NT = EMB / 32;       // 32 K-tiles
  // physical chunk slot for all frag reads (rotation swizzle; see header)
  int ph8 = ((quad + (l15 >> 1)) & 3) * 8;

#define LDSA(b) (lds + (b) * 4096)
#define LDSB(b) (lds + 8192 + (b) * 8192)

  // stage a 64-row x 32-col quarter: 1 gload_lds per thread (4KB).
  // LDS dest linear; slot p=t&3 receives logical chunk (p-(r>>1))&3.
#define ISSUE64(gbase, rowoff, ldst, ktt)                                      \
  { int r_ = (rowoff) + (t >> 2);                                              \
    int g_ = ((t & 3) - ((t >> 3) & 3)) & 3;                                   \
    ld_lds16(&(gbase)[(long)r_ * EMB + (ktt) + g_ * 8],                        \
             (ldst) + ((rowoff) + wid * 16) * 32); }

#define RD_A(mi) { int r_ = (mi) * 16 + l15;                                   \
    af[mi] = *(const bf16x8*)&Ab[r_ * 32 + ph8]; }
#define RD_B(ni) { int r_ = wc * 64 + (ni) * 16 + l15;                         \
    bfr[ni] = *(const bf16x8*)&Bb[r_ * 32 + ph8]; }

#define FENCE asm volatile("" ::: "memory")
#define BAR   { FENCE; __builtin_amdgcn_s_barrier(); FENCE; }

#define MFMAC(nlo)                                                             \
  { __builtin_amdgcn_s_setprio(1);                                             \
    _Pragma("unroll") for (int mi_ = 0; mi_ < 8; ++mi_)                        \
      _Pragma("unroll") for (int nj_ = 0; nj_ < 2; ++nj_)                      \
        acc[mi_][(nlo) + nj_] = __builtin_amdgcn_mfma_f32_16x16x32_bf16(       \
            af[mi_], bfr[(nlo) + nj_], acc[mi_][(nlo) + nj_], 0, 0, 0);        \
    __builtin_amdgcn_s_setprio(0); }

  // prologue: tile0 complete (6 issues) + A0(tile1) in flight
  ISSUE64(Ag, 0,   LDSA(0), 0);
  ISSUE64(Ag, 64,  LDSA(0), 0);
  ISSUE64(Bg, 0,   LDSB(0), 0);
  ISSUE64(Bg, 64,  LDSB(0), 0);
  ISSUE64(Bg, 128, LDSB(0), 0);
  ISSUE64(Bg, 192, LDSB(0), 0);
  ISSUE64(Ag, 0,   LDSA(1), 32);
  asm volatile("s_waitcnt vmcnt(1)" ::: "memory");
  BAR;

#pragma unroll 2
  for (int tt = 0; tt < NT; ++tt) {
    const bf16* Ab = LDSA(tt & 1);
    const bf16* Bb = LDSB(tt & 1);
    bf16* An = LDSA((tt + 1) & 1);
    bf16* Bn = LDSB((tt + 1) & 1);
    bf16* Ac = LDSA(tt & 1);                         // A0(t+2): (tt+2)&1==tt&1
    int kn  = (tt + 1 < NT ? tt + 1 : NT - 1) * 32;  // clamped at tail:
    int kn2 = (tt + 2 < NT ? tt + 2 : NT - 1) * 32;  // dummy identical reload

    // P0: all A frags + low B frags; prefetch A1/B0/B1/B2(t+1)
#pragma unroll
    for (int mi = 0; mi < 8; ++mi) RD_A(mi);
    RD_B(0); RD_B(1);
    ISSUE64(Ag, 64,  An, kn);
    ISSUE64(Bg, 0,   Bn, kn);
    ISSUE64(Bg, 64,  Bn, kn);
    ISSUE64(Bg, 128, Bn, kn);
    BAR; MFMAC(0); BAR;
    // P1: high B frags; prefetch B3(t+1) + A0(t+2) (A reads done in P0)
    RD_B(2); RD_B(3);
    ISSUE64(Bg, 192, Bn, kn);
    ISSUE64(Ag, 0,   Ac, kn2);
    asm volatile("s_waitcnt vmcnt(1)" ::: "memory");  // t+1 fully landed
    BAR; MFMAC(2); BAR;
  }

  asm volatile("s_waitcnt vmcnt(0)" ::: "memory");   // drain clamped DMAs
  __syncthreads();

  // ---------------- epilogue: Q (scaled) / K / V^T scatter ----------------
  int which = bx >> 2;   // tile lies entirely in Q, K, or V
  if (which < 2) {
    bf16* dst = (which == 0) ? q : k;
    float scale = (which == 0) ? QSCALE : 1.0f;
#pragma unroll
    for (int mi = 0; mi < 8; ++mi)
#pragma unroll
      for (int ni = 0; ni < 4; ++ni) {
        int gcol = n0 + wc * 64 + ni * 16 + l15;
        float bv = bias[gcol];
        int e = gcol & 1023, h = e >> 6, d = e & 63;
#pragma unroll
        for (int i = 0; i < 4; ++i) {
          int grow = m0 + mi * 16 + quad * 4 + i;
          int b = grow >> 11, ss = grow & 2047;
          dst[(((long)b * NH + h) * SEQ + ss) * HD + d] =
              (bf16)((acc[mi][ni][i] + bv) * scale);
        }
      }
  } else {
    // V^T scatter (proven: WRITE_SIZE stays ideal, L2 absorbs)
#pragma unroll
    for (int mi = 0; mi < 8; ++mi)
#pragma unroll
      for (int ni = 0; ni < 4; ++ni) {
        int gcol = n0 + wc * 64 + ni * 16 + l15;
        float bv = bias[gcol];
        int e = gcol & 1023, h = e >> 6, d = e & 63;
#pragma unroll
        for (int i = 0; i < 4; ++i) {
          int grow = m0 + mi * 16 + quad * 4 + i;
          int b = grow >> 11, ss = grow & 2047;
          v[(((long)b * NH + h) * HD + d) * SEQ + ss] =
              (bf16)(acc[mi][ni][i] + bv);
        }
      }
  }
#undef LDSA
#undef LDSB
#undef ISSUE64
#undef RD_A
#undef RD_B
#undef MFMAC
}

// ---------------- proj GEMM (R0 known-good): 128x64 tile, 3 blocks/CU ------
__global__ __launch_bounds__(256, 3) void gemm_proj(
    const bf16* __restrict__ A, const bf16* __restrict__ Bt,
    const float* __restrict__ bias, float* __restrict__ out)
{
  __shared__ __align__(16) bf16 Al[128 * 64];
  __shared__ __align__(16) bf16 Bl[64 * 64];
  int lin = blockIdx.x;
  int xcd = lin & 7, s = lin >> 3;
  int bx = s >> 3, by = xcd * 8 + (s & 7);
  int m0 = by * 128;
  int n0 = bx * 64;
  int t = threadIdx.x;
  int wave = t >> 6, lane = t & 63;
  int l15 = lane & 15, quad = lane >> 4;
  int wm = (wave & 1) * 64, wn = (wave >> 1) * 32;

  f32x4 acc[4][2] = {};

  for (int kt = 0; kt < EMB; kt += 64) {
    __syncthreads();
#pragma unroll
    for (int it = 0; it < 4; ++it) {         // A: 128 rows x 8 units
      int c = it * 256 + t;
      int row = c >> 3, u = c & 7;
      ld_lds16(&A[(long)(m0 + row) * EMB + kt + ((u ^ (row & 7)) * 8)],
               &Al[(it * 256 + wave * 64) * 8]);
    }
    {
      int c = t;                              // B: 64 rows x 8 units
      int row = c >> 3, u = c & 7;
      ld_lds16(&Bt[(long)(n0 + row) * EMB + kt + ((u ^ (row & 7)) * 8)],
               &Bl[(wave * 64) * 8]);
      c = 256 + t;
      row = c >> 3; u = c & 7;
      ld_lds16(&Bt[(long)(n0 + row) * EMB + kt + ((u ^ (row & 7)) * 8)],
               &Bl[(256 + wave * 64) * 8]);
    }
    __syncthreads();
#pragma unroll
    for (int ks = 0; ks < 2; ++ks) {
      bf16x8 af[4], bfr[2];
#pragma unroll
      for (int i = 0; i < 4; ++i) {
        int r = wm + i * 16 + l15;
        af[i] = *(const bf16x8*)(&Al[r * 64 + (((ks * 4 + quad) ^ (r & 7)) * 8)]);
      }
#pragma unroll
      for (int i = 0; i < 2; ++i) {
        int r = wn + i * 16 + l15;
        bfr[i] = *(const bf16x8*)(&Bl[r * 64 + (((ks * 4 + quad) ^ (r & 7)) * 8)]);
      }
#pragma unroll
      for (int mi = 0; mi < 4; ++mi)
#pragma unroll
        for (int ni = 0; ni < 2; ++ni)
          acc[mi][ni] = __builtin_amdgcn_mfma_f32_16x16x32_bf16(af[mi], bfr[ni], acc[mi][ni], 0, 0, 0);
    }
  }

#pragma unroll
  for (int mi = 0; mi < 4; ++mi)
#pragma unroll
    for (int ni = 0; ni < 2; ++ni) {
      int gcol = n0 + wn + ni * 16 + l15;
      float bv = bias[gcol];
#pragma unroll
      for (int i = 0; i < 4; ++i) {
        int grow = m0 + wm + mi * 16 + quad * 4 + i;
        out[(long)grow * EMB + gcol] = acc[mi][ni][i] + bv;
      }
    }
}

// ---------------- flash attention (double-buffered K/V, counted vmcnt) -----
// 1D grid 512 blocks; block 256 = 4 waves x 32 q-rows = 128-row strip.
// Decode: xcd=L&7, a=L>>3; head = xcd + 8*(a&7); strip = a>>3; block runs
// strips st and 15-st. Per tile: 4 DMAs/thread (K 2, V 2). Pipeline:
// prologue stages tile0; iter t issues tile t+1 into buf^1, waits vmcnt(4)
// (tile t landed, t+1 in flight), raw s_barrier, computes buf, barrier.
#define LDP 72   // P row stride (elems): conflict-free, 16B-aligned

__global__ __launch_bounds__(256, 2) void attn(
    const bf16* __restrict__ Q, const bf16* __restrict__ K,
    const bf16* __restrict__ Vt, bf16* __restrict__ Y)
{
  __shared__ __align__(16) bf16 Kl[2][64 * 64];     // 16 KB
  __shared__ __align__(16) bf16 Vl[2][64 * 64];     // 16 KB
  __shared__ __align__(16) bf16 Pl[4][32 * LDP];    // 18 KB, per-wave
  int L = blockIdx.x;
  int a = L >> 3;
  int hd = (L & 7) + 8 * (a & 7);
  int st = a >> 3;
  int b = hd >> 4, h = hd & 15;
  const bf16* Qp  = Q  + (((long)b * NH + h) * SEQ) * HD;
  const bf16* Kp  = K  + (((long)b * NH + h) * SEQ) * HD;
  const bf16* Vtp = Vt + (((long)b * NH + h) * HD) * SEQ;
  int t = threadIdx.x, wave = t >> 6, lane = t & 63;
  int l15 = lane & 15, quad = lane >> 4;

#define AFENCE asm volatile("" ::: "memory")
#define ABAR   { AFENCE; __builtin_amdgcn_s_barrier(); AFENCE; }
  // stage tile kt_ (64 keys) into buffer bf_: 4 DMAs per thread
#define STAGE(kt_, bf_)                                                        \
  { int k0_ = (kt_) * 64;                                                      \
    _Pragma("unroll") for (int it_ = 0; it_ < 2; ++it_) {                      \
      int cu_ = it_ * 256 + t;                                                 \
      int row_ = cu_ >> 3, u_ = cu_ & 7;                                       \
      ld_lds16(&Kp[(long)(k0_ + row_) * HD + ((u_ ^ (row_ & 7)) * 8)],         \
               &Kl[bf_][(it_ * 256 + wave * 64) * 8]);                         \
      ld_lds16(&Vtp[(long)row_ * SEQ + k0_ + ((u_ ^ (row_ & 7)) * 8)],         \
               &Vl[bf_][(it_ * 256 + wave * 64) * 8]); } }

#pragma unroll 1
  for (int pass = 0; pass < 2; ++pass) {
    int q0 = (pass == 0) ? st * 128 : (SEQ - 128) - st * 128;
    int wq0 = q0 + wave * 32;

    // Q fragments: m-frag m covers rows wq0+m*16 .. +15; k split 0/32
    bf16x8 qf[2][2];
#pragma unroll
    for (int m = 0; m < 2; ++m) {
      const bf16* qrow = Qp + (long)(wq0 + m * 16 + l15) * HD + quad * 8;
      qf[m][0] = *(const bf16x8*)(qrow);
      qf[m][1] = *(const bf16x8*)(qrow + 32);
    }
    float lrow[2][4] = {};
    f32x4 oacc[2][4] = {};

    int ntiles = q0 / 64 + 2;     // block's 128 rows need tiles through q0+127
    STAGE(0, 0);                  // prologue: tile 0 in flight (4/thread)
#pragma unroll 1
    for (int kt = 0; kt < ntiles; ++kt) {
      int k0 = kt * 64;
      int cur = kt & 1;
      if (kt + 1 < ntiles) {
        STAGE(kt + 1, cur ^ 1);   // 4 more in flight (overwrites buf read at
                                  // tile kt-1; all reads done before iter
                                  // kt-1's trailing barrier)
        asm volatile("s_waitcnt vmcnt(4)" ::: "memory");  // tile kt landed
      } else {
        asm volatile("s_waitcnt vmcnt(0)" ::: "memory");  // final drain
      }
      ABAR;                       // all waves' tile-kt data visible

      if (k0 <= wq0 + 31) {       // wave-uniform; barriers stay uniform
        const bf16* Kc = Kl[cur];
        const bf16* Vc = Vl[cur];
        // scores: S[32q x 64k]; kfr register-shared across both m-frags
        f32x4 sc[2][4] = {};
#pragma unroll
        for (int kk = 0; kk < 2; ++kk) {
#pragma unroll
          for (int ni = 0; ni < 4; ++ni) {
            int r = ni * 16 + l15, u = kk * 4 + quad;
            bf16x8 kfr = *(const bf16x8*)(&Kc[r * 64 + ((u ^ (r & 7)) * 8)]);
            sc[0][ni] = __builtin_amdgcn_mfma_f32_16x16x32_bf16(qf[0][kk], kfr, sc[0][ni], 0, 0, 0);
            sc[1][ni] = __builtin_amdgcn_mfma_f32_16x16x32_bf16(qf[1][kk], kfr, sc[1][ni], 0, 0, 0);
          }
        }

        bool full = (k0 + 63 <= wq0);   // wave-uniform (min row = wq0)
#pragma unroll
        for (int m = 0; m < 2; ++m) {
#pragma unroll
          for (int i = 0; i < 4; ++i) {
            int qr = wq0 + m * 16 + quad * 4 + i;
            float e[4];
#pragma unroll
            for (int ni = 0; ni < 4; ++ni) {
              float x = sc[m][ni][i];
              if (!full) x = (k0 + ni * 16 + l15 <= qr) ? x : -1e30f;
              e[ni] = __builtin_amdgcn_exp2f(x);
            }
            lrow[m][i] += (e[0] + e[1]) + (e[2] + e[3]);
            int prow = (m * 16 + quad * 4 + i) * LDP;
#pragma unroll
            for (int ni = 0; ni < 4; ++ni)
              Pl[wave][prow + ni * 16 + l15] = (bf16)e[ni];
          }
        }
        asm volatile("s_waitcnt lgkmcnt(0)" ::: "memory");
        // PV: P[32x64] @ V[64x64]; vf register-shared across both m-frags
#pragma unroll
        for (int kk = 0; kk < 2; ++kk) {
          int kbase = kk * 32 + quad * 8;
          bf16x8 pf0 = *(const bf16x8*)(&Pl[wave][(l15) * LDP + kbase]);
          bf16x8 pf1 = *(const bf16x8*)(&Pl[wave][(16 + l15) * LDP + kbase]);
#pragma unroll
          for (int ni = 0; ni < 4; ++ni) {
            int dd = ni * 16 + l15, u = kk * 4 + quad;
            bf16x8 vf = *(const bf16x8*)(&Vc[dd * 64 + ((u ^ (dd & 7)) * 8)]);
            oacc[0][ni] = __builtin_amdgcn_mfma_f32_16x16x32_bf16(pf0, vf, oacc[0][ni], 0, 0, 0);
            oacc[1][ni] = __builtin_amdgcn_mfma_f32_16x16x32_bf16(pf1, vf, oacc[1][ni], 0, 0, 0);
          }
        }
      }
      ABAR;                       // reads done before next iter's DMA issue
    }
    // epilogue: reduce l across the 16-lane column groups, write Y bf16
#pragma unroll
    for (int m = 0; m < 2; ++m) {
#pragma unroll
      for (int i = 0; i < 4; ++i) {
        float rs = lrow[m][i];
#pragma unroll
        for (int off = 8; off; off >>= 1) rs += __shfl_xor(rs, off, 16);
        float inv = 1.0f / rs;
        int qr = wq0 + m * 16 + quad * 4 + i;
        bf16* dst = Y + ((long)(b * SEQ + qr)) * EMB + h * HD;
#pragma unroll
        for (int ni = 0; ni < 4; ++ni)
          dst[ni * 16 + l15] = (bf16)(oacc[m][ni][i] * inv);
      }
    }
  }
#undef STAGE
#undef ABAR
#undef AFENCE
}

extern "C" void kernel_launch(void* const* d_in, const int* in_sizes, int n_in,
                              void* d_out, int out_size, void* d_ws, size_t ws_size,
                              hipStream_t stream) {
  const float* x      = (const float*)d_in[0];
  const float* W_attn = (const float*)d_in[1];
  const float* b_attn = (const float*)d_in[2];
  const float* W_proj = (const float*)d_in[3];
  const float* b_proj = (const float*)d_in[4];
  float* out = (float*)d_out;
  char* ws = (char*)d_ws;
  bf16* xb  = (bf16*)(ws);                 // 16.78 MB
  bf16* WaT = (bf16*)(ws + 16777216);      //  6.29 MB
  bf16* WpT = (bf16*)(ws + 23068672);      //  2.10 MB
  bf16* Qb  = (bf16*)(ws + 25165824);      // 16.78 MB (pre-scaled)
  bf16* Kb  = (bf16*)(ws + 41943040);      // 16.78 MB
  bf16* Vtb = (bf16*)(ws + 58720256);      // 16.78 MB (transposed [b,h,d,s])
  bf16* Yb  = (bf16*)(ws + 75497472);      // 16.78 MB

  cvt_f32_bf16<<<8192, 256, 0, stream>>>(x, xb, BATCH * SEQ * EMB);
  transpose_cvt2<<<dim3(128, 32), 256, 0, stream>>>(W_attn, W_proj, WaT, WpT);
  gemm8p<<<768, 256, 0, stream>>>(xb, WaT, b_attn, Qb, Kb, Vtb);
  attn<<<512, 256, 0, stream>>>(Qb, Kb, Vtb, Yb);
  gemm_proj<<<1024, 256, 0, stream>>>(Yb, WpT, b_proj, out);
}